// Round 9
// baseline (171.782 us; speedup 1.0000x reference)
//
#include <hip/hip_runtime.h>
#include <math.h>

#define BATCH 8
#define T 2048
#define H 1024
#define D 64

typedef __attribute__((ext_vector_type(8))) short bf16x8;
typedef __attribute__((ext_vector_type(4))) short bf16x4;
typedef __attribute__((ext_vector_type(4))) float f32x4;

__device__ __forceinline__ short f2bf(float f) {
  union { float f; unsigned u; } x; x.f = f;
  return (short)((x.u + 0x7FFFu + ((x.u >> 16) & 1u)) >> 16);
}

#define MFMA(a, b, c) __builtin_amdgcn_mfma_f32_16x16x32_bf16(a, b, c, 0, 0, 0)

// 16x16x16 bf16 MFMA (P^T is born in its B-operand layout). Host pass sees
// neither builtin -> shuffle fallback (parses everywhere; NO #error).
#if __has_builtin(__builtin_amdgcn_mfma_f32_16x16x16bf16_1k)
#define MFMA16(a, b, c) __builtin_amdgcn_mfma_f32_16x16x16bf16_1k(a, b, c, 0, 0, 0)
#define HAVE_MFMA16 1
#elif __has_builtin(__builtin_amdgcn_mfma_f32_16x16x16_bf16)
#define MFMA16(a, b, c) __builtin_amdgcn_mfma_f32_16x16x16_bf16(a, b, c, 0, 0, 0)
#define HAVE_MFMA16 1
#else
#define HAVE_MFMA16 0
#endif

#define NCHUNK_MAX 11  // ceil(32/3) chunks of 3 k-tiles

// ---------------------------------------------------------------------------
// Kernel 1: W [1024][64] fp32 -> Wt[3][64 n][1024 k] bf16 (transposed).
// which 0 = Wq (pre-scaled by 0.125*log2e so attention uses exp2 directly).
// ---------------------------------------------------------------------------
__global__ __launch_bounds__(256) void prep_w(
    const float* __restrict__ Wq, const float* __restrict__ Wk,
    const float* __restrict__ Wv, short* __restrict__ Wt) {
  const int which = blockIdx.y;
  const float* W = which == 0 ? Wq : which == 1 ? Wk : Wv;
  const float scale = which == 0 ? 0.125f * 1.44269504088896340736f : 1.0f;
  const int kbase = blockIdx.x * 64;
  const int n = threadIdx.x & 63;
  const int k0 = threadIdx.x >> 6;
  short* dst = Wt + (size_t)which * (D * H);
#pragma unroll
  for (int i = 0; i < 16; ++i) {
    int k = kbase + i * 4 + k0;
    dst[n * H + k] = f2bf(W[(size_t)k * D + n] * scale);
  }
}

// ---------------------------------------------------------------------------
// Kernel 2: q/k/v projection — barrier-free split-K GEMM (R8 body).
// KEY CHANGE vs R8: __launch_bounds__(256, 3). All prior proj variants got
// VGPR_Count 36-80 (compiler minimized regs for an occupancy LDS can't
// reach anyway) -> ~2-3 loads in flight -> full-latency serialization of
// every load+MFMA chunk (R5-R8 all 38-65 µs, everything idle in PMC).
// 3 waves/EU (= the 3 blocks/CU that 48 KB LDS permits) caps VGPR at ~170:
// 12 b-loads + 2 x-loads per k-step can ALL be in flight, 2 k-steps deep.
// ---------------------------------------------------------------------------
__global__ __launch_bounds__(256, 3) void proj_mfma(
    const float* __restrict__ x, const short* __restrict__ Wt,
    short* __restrict__ qb, short* __restrict__ kb, short* __restrict__ vT) {
  __shared__ float red[4][12][64][4];  // 48 KB
  const int tid = threadIdx.x;
  const int lane = tid & 63, wv = tid >> 6;
  const int l15 = lane & 15, quad = lane >> 4;
  const int row0 = blockIdx.x * 16;

  // wave wv covers k in [wv*256, wv*256+256)
  const float* xr = x + (size_t)(row0 + l15) * H + wv * 256 + quad * 8;
  const short* wb = Wt + (size_t)l15 * H + wv * 256 + quad * 8;

  f32x4 acc[12] = {};
#pragma unroll
  for (int it = 0; it < 8; ++it) {  // k-step 32, no barriers anywhere
    float4 f0 = *(const float4*)(xr + it * 32);
    float4 f1 = *(const float4*)(xr + it * 32 + 4);
    bf16x8 a;
    a[0] = f2bf(f0.x); a[1] = f2bf(f0.y); a[2] = f2bf(f0.z); a[3] = f2bf(f0.w);
    a[4] = f2bf(f1.x); a[5] = f2bf(f1.y); a[6] = f2bf(f1.z); a[7] = f2bf(f1.w);
#pragma unroll
    for (int nf = 0; nf < 12; ++nf) {
      bf16x8 b = *(const bf16x8*)(wb + (size_t)(nf >> 2) * (D * H) +
                                  (size_t)((nf & 3) * 16) * H + it * 32);
      acc[nf] = MFMA(a, b, acc[nf]);
    }
  }

  // cross-wave K reduction via LDS (single barrier in the whole kernel)
#pragma unroll
  for (int nf = 0; nf < 12; ++nf)
    *(f32x4*)&red[wv][nf][lane][0] = acc[nf];
  __syncthreads();

#pragma unroll
  for (int i = 0; i < 3; ++i) {
    const int nf = wv * 3 + i;
    f32x4 s0 = *(const f32x4*)&red[0][nf][lane][0];
    f32x4 s1 = *(const f32x4*)&red[1][nf][lane][0];
    f32x4 s2 = *(const f32x4*)&red[2][nf][lane][0];
    f32x4 s3 = *(const f32x4*)&red[3][nf][lane][0];
    f32x4 s;
#pragma unroll
    for (int r = 0; r < 4; ++r) s[r] = (s0[r] + s1[r]) + (s2[r] + s3[r]);

    const int w3 = nf >> 2;
    const int d = (nf & 3) * 16 + l15;
    if (w3 < 2) {  // q / k: [row][d]
      short* dst = (w3 == 0) ? qb : kb;
#pragma unroll
      for (int r = 0; r < 4; ++r)
        dst[(size_t)(row0 + quad * 4 + r) * D + d] = f2bf(s[r]);
    } else {  // v -> vT[b][d][t], 4 consecutive t pack into one 8B store
      const int bb = row0 >> 11, t0 = (row0 & 2047) + quad * 4;
      short4 pk = make_short4(f2bf(s[0]), f2bf(s[1]), f2bf(s[2]), f2bf(s[3]));
      *(short4*)(vT + ((size_t)(bb * D + d)) * T + t0) = pk;
    }
  }
}

// ---------------------------------------------------------------------------
// Kernel 3: transposed flash attention, split-K, whole-chunk staging
// (R5-verified body). KEY CHANGE: __launch_bounds__(256, 3) — same VGPR
// starvation fix (was 52-60 regs; chunk's 12 staging loads serialized).
// ---------------------------------------------------------------------------
__global__ __launch_bounds__(256, 3) void attn_mfma(
    const short* __restrict__ qbuf, const short* __restrict__ kbuf,
    const short* __restrict__ vT, float* __restrict__ out,
    float* __restrict__ Opart, float* __restrict__ lpart, int mode) {
  __shared__ short Ks[192][72];   // 27648 B
  __shared__ short Vs[64][200];   // 25600 B  (total 53248 B)

  const int g = blockIdx.x;
  int b, qt, c;
  if (mode == 0) {
    b = g >> 5; qt = g & 31; c = 0;
  } else {
    b = g / 187;
    int r = g - b * 187;
    qt = 0; c = 0;
    for (int gg = 0;; ++gg) {
      const int cnt = (gg < 10) ? 3 * (gg + 1) : 22;
      if (r < cnt) { qt = 3 * gg + r / (gg + 1); c = r - (r / (gg + 1)) * (gg + 1); break; }
      r -= cnt;
    }
  }
  const int kt0 = c * 3;
  const int kt1 = (mode == 0) ? (qt + 1) : min(kt0 + 3, qt + 1);

  const int tid = threadIdx.x;
  const int lane = tid & 63, wv = tid >> 6;
  const int l15 = lane & 15, quad = lane >> 4;
  const int qrow = qt * 64 + wv * 16 + l15;

  const short* qp = qbuf + (size_t)(b * T + qrow) * D;
  bf16x8 qf0 = *(const bf16x8*)(qp + quad * 8);
  bf16x8 qf1 = *(const bf16x8*)(qp + 32 + quad * 8);

  const int srow = tid >> 2, soff = (tid & 3) * 16;
  const short* kbb = kbuf + (size_t)b * T * D;
  const short* vbb = vT + (size_t)b * D * T;

  f32x4 o[4] = {};
  float lsum = 0.f;

  for (int base = kt0; base < kt1; base += 3) {
    const int nt3 = min(3, kt1 - base);
    if (base > kt0) __syncthreads();
    for (int t3 = 0; t3 < nt3; ++t3) {
      const bf16x8* kp = (const bf16x8*)(kbb + (size_t)((base + t3) * 64 + srow) * D + soff);
      bf16x8 k0 = kp[0], k1 = kp[1];
      const bf16x8* vp = (const bf16x8*)(vbb + (size_t)srow * T + (base + t3) * 64 + soff);
      bf16x8 v0 = vp[0], v1 = vp[1];
      *(bf16x8*)&Ks[t3 * 64 + srow][soff] = k0;
      *(bf16x8*)&Ks[t3 * 64 + srow][soff + 8] = k1;
      *(bf16x8*)&Vs[srow][t3 * 64 + soff] = v0;
      *(bf16x8*)&Vs[srow][t3 * 64 + soff + 8] = v1;
    }
    __syncthreads();

    for (int tt = 0; tt < nt3; ++tt) {
      const int kt = base + tt;
      f32x4 s[4] = {};
#pragma unroll
      for (int nt = 0; nt < 4; ++nt) {
        bf16x8 ka0 = *(const bf16x8*)&Ks[tt * 64 + nt * 16 + l15][quad * 8];
        bf16x8 ka1 = *(const bf16x8*)&Ks[tt * 64 + nt * 16 + l15][32 + quad * 8];
        s[nt] = MFMA(ka1, qf1, MFMA(ka0, qf0, s[nt]));
      }
      const bool diag = (kt == qt);
#pragma unroll
      for (int nt = 0; nt < 4; ++nt) {
#pragma unroll
        for (int r = 0; r < 4; ++r) {
          float p = exp2f(s[nt][r]);
          if (diag) {
            int key = kt * 64 + nt * 16 + quad * 4 + r;
            if (key > qrow) p = 0.f;
          }
          lsum += p;
          s[nt][r] = p;
        }
      }
#if HAVE_MFMA16
#pragma unroll
      for (int nt = 0; nt < 4; ++nt) {
        bf16x4 pb;
        pb[0] = f2bf(s[nt][0]); pb[1] = f2bf(s[nt][1]);
        pb[2] = f2bf(s[nt][2]); pb[3] = f2bf(s[nt][3]);
#pragma unroll
        for (int dt = 0; dt < 4; ++dt) {
          bf16x4 va = *(const bf16x4*)&Vs[dt * 16 + l15][tt * 64 + nt * 16 + quad * 4];
          o[dt] = MFMA16(va, pb, o[dt]);
        }
      }
#else
#pragma unroll
      for (int h = 0; h < 2; ++h) {
        union { short2 s2; int i2; } a01, a23, b01, b23;
        a01.s2 = make_short2(f2bf(s[2 * h][0]), f2bf(s[2 * h][1]));
        a23.s2 = make_short2(f2bf(s[2 * h][2]), f2bf(s[2 * h][3]));
        b01.s2 = make_short2(f2bf(s[2 * h + 1][0]), f2bf(s[2 * h + 1][1]));
        b23.s2 = make_short2(f2bf(s[2 * h + 1][2]), f2bf(s[2 * h + 1][3]));
        const int srcA = l15 + ((quad & 1) << 5);
        const int srcB = srcA + 16;
        int gA01 = __shfl(a01.i2, srcA), gA01b = __shfl(b01.i2, srcA);
        int gA23 = __shfl(a23.i2, srcA), gA23b = __shfl(b23.i2, srcA);
        int gB01 = __shfl(a01.i2, srcB), gB01b = __shfl(b01.i2, srcB);
        int gB23 = __shfl(a23.i2, srcB), gB23b = __shfl(b23.i2, srcB);
        union { int d[4]; bf16x8 v; } pf;
        const bool lo = (quad < 2);
        pf.d[0] = lo ? gA01 : gA01b;
        pf.d[1] = lo ? gA23 : gA23b;
        pf.d[2] = lo ? gB01 : gB01b;
        pf.d[3] = lo ? gB23 : gB23b;
#pragma unroll
        for (int dt = 0; dt < 4; ++dt) {
          bf16x8 va = *(const bf16x8*)&Vs[dt * 16 + l15][tt * 64 + h * 32 + quad * 8];
          o[dt] = MFMA(va, pf.v, o[dt]);
        }
      }
#endif
    }
  }

  float lv = lsum;
  lv += __shfl_xor(lv, 16);
  lv += __shfl_xor(lv, 32);

  if (kt0 == 0 && kt1 == qt + 1) {
    const float inv = 1.0f / lv;
    float* op = out + (size_t)(b * T + qrow) * D;
#pragma unroll
    for (int dt = 0; dt < 4; ++dt)
      *(float4*)(op + dt * 16 + quad * 4) =
          make_float4(o[dt][0] * inv, o[dt][1] * inv, o[dt][2] * inv, o[dt][3] * inv);
  } else {
    const int prow = b * T + qrow;
    float* pp = Opart + ((size_t)c * 16384 + prow) * D;
#pragma unroll
    for (int dt = 0; dt < 4; ++dt)
      *(float4*)(pp + dt * 16 + quad * 4) =
          make_float4(o[dt][0], o[dt][1], o[dt][2], o[dt][3]);
    if (quad == 0) lpart[c * 16384 + prow] = lv;
  }
}

// ---------------------------------------------------------------------------
// Kernel 4: combine split-K partials for rows with >=2 chunks (qrow >= 192).
// ---------------------------------------------------------------------------
__global__ __launch_bounds__(256) void combine_k(
    const float* __restrict__ Opart, const float* __restrict__ lpart,
    float* __restrict__ out) {
  const int gid = blockIdx.x * 256 + threadIdx.x;  // 928*256 = 237568
  const int r16 = gid >> 4;                        // 0..14847
  const int b = r16 / 1856;
  const int qrow = 192 + (r16 - b * 1856);
  const int row = b * T + qrow;
  const int d4 = (gid & 15) << 2;
  const int nc = (qrow >> 6) / 3 + 1;  // 2..11 chunks
  float a0 = 0.f, a1 = 0.f, a2 = 0.f, a3 = 0.f, l = 0.f;
  for (int c = 0; c < nc; ++c) {
    const float4 t = *(const float4*)(Opart + ((size_t)c * 16384 + row) * D + d4);
    a0 += t.x; a1 += t.y; a2 += t.z; a3 += t.w;
    l += lpart[c * 16384 + row];
  }
  const float inv = 1.0f / l;
  *(float4*)(out + (size_t)row * D + d4) = make_float4(a0 * inv, a1 * inv, a2 * inv, a3 * inv);
}

// ---------------------------------------------------------------------------
extern "C" void kernel_launch(void* const* d_in, const int* in_sizes, int n_in,
                              void* d_out, int out_size, void* d_ws, size_t ws_size,
                              hipStream_t stream) {
  const float* x  = (const float*)d_in[0];
  const float* Wk = (const float*)d_in[1];
  const float* Wq = (const float*)d_in[2];
  const float* Wv = (const float*)d_in[3];
  float* out = (float*)d_out;

  const size_t M = (size_t)BATCH * T * D;  // 1,048,576 elements
  short* qb = (short*)d_ws;
  short* kb = qb + M;
  short* vT = kb + M;
  short* Wt = vT + M;                       // 196,608 shorts
  float* Opart = (float*)(Wt + 196608);
  float* lpart = Opart + (size_t)NCHUNK_MAX * 16384 * 64;

  const size_t need = (3 * M + 196608) * 2 +
                      ((size_t)NCHUNK_MAX * 16384 * 64 + (size_t)NCHUNK_MAX * 16384) * 4;
  const bool split = ws_size >= need;

  prep_w<<<dim3(16, 3), 256, 0, stream>>>(Wq, Wk, Wv, Wt);
  proj_mfma<<<dim3(1024), 256, 0, stream>>>(x, Wt, qb, kb, vT);
  if (split) {
    attn_mfma<<<dim3(1496), 256, 0, stream>>>(qb, kb, vT, out, Opart, lpart, 1);
    combine_k<<<dim3(928), 256, 0, stream>>>(Opart, lpart, out);
  } else {
    attn_mfma<<<dim3(256), 256, 0, stream>>>(qb, kb, vT, out, Opart, lpart, 0);
  }
}

// Round 10
// 146.412 us; speedup vs baseline: 1.1733x; 1.1733x over previous
//
#include <hip/hip_runtime.h>
#include <math.h>

#define BATCH 8
#define T 2048
#define H 1024
#define D 64

typedef __attribute__((ext_vector_type(8))) short bf16x8;
typedef __attribute__((ext_vector_type(4))) short bf16x4;
typedef __attribute__((ext_vector_type(4))) float f32x4;

__device__ __forceinline__ short f2bf(float f) {
  union { float f; unsigned u; } x; x.f = f;
  return (short)((x.u + 0x7FFFu + ((x.u >> 16) & 1u)) >> 16);
}

#define MFMA(a, b, c) __builtin_amdgcn_mfma_f32_16x16x32_bf16(a, b, c, 0, 0, 0)

#if __has_builtin(__builtin_amdgcn_mfma_f32_16x16x16bf16_1k)
#define MFMA16(a, b, c) __builtin_amdgcn_mfma_f32_16x16x16bf16_1k(a, b, c, 0, 0, 0)
#define HAVE_MFMA16 1
#elif __has_builtin(__builtin_amdgcn_mfma_f32_16x16x16_bf16)
#define MFMA16(a, b, c) __builtin_amdgcn_mfma_f32_16x16x16_bf16(a, b, c, 0, 0, 0)
#define HAVE_MFMA16 1
#else
#define HAVE_MFMA16 0
#endif

// Async global->LDS, width 16 B/lane. HW writes wave-uniform base + lane*16
// (m104/m108) — so the LDS arg is the BASE; the fallback adds lane manually.
__device__ __forceinline__ void gload16(const void* g, void* lbase, int lane) {
#if __has_builtin(__builtin_amdgcn_global_load_lds)
  typedef __attribute__((address_space(1))) unsigned int g_uint;
  typedef __attribute__((address_space(3))) unsigned int l_uint;
  __builtin_amdgcn_global_load_lds((g_uint*)(void*)g, (l_uint*)lbase, 16, 0, 0);
#else
  *(float4*)((char*)lbase + lane * 16) = *(const float4*)g;
#endif
}

#define NCHUNK_MAX 11  // ceil(32/3) chunks of 3 k-tiles

// ---------------------------------------------------------------------------
// Kernel 1: W [1024][64] fp32 -> Wt[3][64 n][1024 k] bf16 (transposed).
// which 0 = Wq (pre-scaled by 0.125*log2e so attention uses exp2 directly).
// ---------------------------------------------------------------------------
__global__ __launch_bounds__(256) void prep_w(
    const float* __restrict__ Wq, const float* __restrict__ Wk,
    const float* __restrict__ Wv, short* __restrict__ Wt) {
  const int which = blockIdx.y;
  const float* W = which == 0 ? Wq : which == 1 ? Wk : Wv;
  const float scale = which == 0 ? 0.125f * 1.44269504088896340736f : 1.0f;
  const int kbase = blockIdx.x * 64;
  const int n = threadIdx.x & 63;
  const int k0 = threadIdx.x >> 6;
  short* dst = Wt + (size_t)which * (D * H);
#pragma unroll
  for (int i = 0; i < 16; ++i) {
    int k = kbase + i * 4 + k0;
    dst[n * H + k] = f2bf(W[(size_t)k * D + n] * scale);
  }
}

// ---------------------------------------------------------------------------
// Kernel 2: q/k/v projection — m97-style GEMM.
// R5-R9 lesson: VGPR-resident staging can't pipeline (scheduler holds ~6
// load results max; launch_bounds headroom unused — R9 falsified that).
// Fix = global_load_lds: staging loads have NO VGPR result, queue in HW.
// Block 64M x 96N (grid 512, 2/CU at 56 KB LDS), BK=64, DOUBLE-buffered:
// per iter: barrier (drains stage issued one compute-section ago) ->
// issue stage k+1 (async) -> compute k. A stays fp32 in LDS (cvt at frag
// read); global-side XOR swizzle (A: kc^(r&15), B: kc^(r&7)) gives 2-way
// bank aliasing (= free, m136) on frag reads despite lane*16 DMA layout.
// ---------------------------------------------------------------------------
__global__ __launch_bounds__(256) void proj_mfma(
    const float* __restrict__ x, const short* __restrict__ Wt,
    short* __restrict__ qb, short* __restrict__ kb, short* __restrict__ vT) {
  __shared__ float As[2][64 * 64];  // 2 x 16 KB, fp32, swizzled chunks
  __shared__ short Bs[2][96 * 64];  // 2 x 12 KB, bf16, swizzled chunks
  const int tid = threadIdx.x;
  const int lane = tid & 63, wv = tid >> 6;
  const int l15 = lane & 15, quad = lane >> 4;
  const int mtile = blockIdx.x >> 1;
  const int nhalf = blockIdx.x & 1;
  const int row_base = mtile * 64;
  const int n0 = nhalf * 96;  // flat n row into Wt viewed as [192][1024]

  // per-thread staging source pointers (k0 added per iter)
  const float* gA[4];
#pragma unroll
  for (int j = 0; j < 4; ++j) {
    const int r = wv * 16 + j * 4 + (lane >> 4);           // local A row
    const int kc = (lane & 15) ^ ((j * 4 + (lane >> 4)) & 15);
    gA[j] = x + (size_t)(row_base + r) * H + kc * 4;
  }
  const short* gB[3];
#pragma unroll
  for (int j = 0; j < 3; ++j) {
    const int r = wv * 24 + j * 8 + (lane >> 3);           // local B row
    const int kc = (lane & 7) ^ (lane >> 3);
    gB[j] = Wt + (size_t)(n0 + r) * H + kc * 8;
  }

  f32x4 acc[2][3] = {};  // [m-frag][n-frag], 24 VGPRs

  // prologue: stage tile 0 into buf 0
#pragma unroll
  for (int j = 0; j < 4; ++j) gload16(gA[j], &As[0][(wv * 16 + j * 4) * 64], lane);
#pragma unroll
  for (int j = 0; j < 3; ++j) gload16(gB[j], &Bs[0][(wv * 24 + j * 8) * 64], lane);

  for (int it = 0; it < 16; ++it) {
    const int cur = it & 1;
    __syncthreads();  // drains stage of tile `it` (issued one compute ago)
    if (it + 1 < 16) {  // async stage tile it+1 into the other buffer
      const int ko = (it + 1) * 64;
#pragma unroll
      for (int j = 0; j < 4; ++j)
        gload16(gA[j] + ko, &As[cur ^ 1][(wv * 16 + j * 4) * 64], lane);
#pragma unroll
      for (int j = 0; j < 3; ++j)
        gload16(gB[j] + ko, &Bs[cur ^ 1][(wv * 24 + j * 8) * 64], lane);
    }

    // compute tile `it` from buf cur
    const float* Ab = As[cur];
    const short* Bb = Bs[cur];
    bf16x8 afr[2][2];
#pragma unroll
    for (int kk = 0; kk < 2; ++kk)
#pragma unroll
      for (int mt = 0; mt < 2; ++mt) {
        const int r = (wv & 1) * 32 + mt * 16 + l15;
        const int kc0 = kk * 8 + quad * 2;
        f32x4 lo = *(const f32x4*)&Ab[r * 64 + ((kc0 ^ (r & 15)) * 4)];
        f32x4 hi = *(const f32x4*)&Ab[r * 64 + (((kc0 + 1) ^ (r & 15)) * 4)];
        bf16x8 a;
        a[0] = f2bf(lo[0]); a[1] = f2bf(lo[1]); a[2] = f2bf(lo[2]); a[3] = f2bf(lo[3]);
        a[4] = f2bf(hi[0]); a[5] = f2bf(hi[1]); a[6] = f2bf(hi[2]); a[7] = f2bf(hi[3]);
        afr[kk][mt] = a;
      }
#pragma unroll
    for (int kk = 0; kk < 2; ++kk)
#pragma unroll
      for (int nt = 0; nt < 3; ++nt) {
        const int r = (wv >> 1) * 48 + nt * 16 + l15;
        const int kc = kk * 4 + quad;
        bf16x8 b = *(const bf16x8*)&Bb[r * 64 + ((kc ^ (r & 7)) * 8)];
        acc[0][nt] = MFMA(afr[kk][0], b, acc[0][nt]);
        acc[1][nt] = MFMA(afr[kk][1], b, acc[1][nt]);
      }
  }

  // epilogue: row = row_base + (wv&1)*32 + mt*16 + quad*4 + r
  //           col gnt = nhalf*6 + (wv>>1)*3 + nt, d = (gnt&3)*16 + l15
#pragma unroll
  for (int nt = 0; nt < 3; ++nt) {
    const int gnt = nhalf * 6 + (wv >> 1) * 3 + nt;
    const int w3 = gnt >> 2;
    const int d = (gnt & 3) * 16 + l15;
#pragma unroll
    for (int mt = 0; mt < 2; ++mt) {
      const int row0 = row_base + (wv & 1) * 32 + mt * 16 + quad * 4;
      if (w3 < 2) {
        short* dst = (w3 == 0) ? qb : kb;
#pragma unroll
        for (int r = 0; r < 4; ++r)
          dst[(size_t)(row0 + r) * D + d] = f2bf(acc[mt][nt][r]);
      } else {
        const int bb = row0 >> 11, t0 = row0 & 2047;
        short4 pk = make_short4(f2bf(acc[mt][nt][0]), f2bf(acc[mt][nt][1]),
                                f2bf(acc[mt][nt][2]), f2bf(acc[mt][nt][3]));
        *(short4*)(vT + ((size_t)(bb * D + d)) * T + t0) = pk;
      }
    }
  }
}

// ---------------------------------------------------------------------------
// Kernel 3: transposed flash attention, split-K, whole-chunk staging
// (R5-verified body, unchanged).
// ---------------------------------------------------------------------------
__global__ __launch_bounds__(256) void attn_mfma(
    const short* __restrict__ qbuf, const short* __restrict__ kbuf,
    const short* __restrict__ vT, float* __restrict__ out,
    float* __restrict__ Opart, float* __restrict__ lpart, int mode) {
  __shared__ short Ks[192][72];   // 27648 B
  __shared__ short Vs[64][200];   // 25600 B  (total 53248 B)

  const int g = blockIdx.x;
  int b, qt, c;
  if (mode == 0) {
    b = g >> 5; qt = g & 31; c = 0;
  } else {
    b = g / 187;
    int r = g - b * 187;
    qt = 0; c = 0;
    for (int gg = 0;; ++gg) {
      const int cnt = (gg < 10) ? 3 * (gg + 1) : 22;
      if (r < cnt) { qt = 3 * gg + r / (gg + 1); c = r - (r / (gg + 1)) * (gg + 1); break; }
      r -= cnt;
    }
  }
  const int kt0 = c * 3;
  const int kt1 = (mode == 0) ? (qt + 1) : min(kt0 + 3, qt + 1);

  const int tid = threadIdx.x;
  const int lane = tid & 63, wv = tid >> 6;
  const int l15 = lane & 15, quad = lane >> 4;
  const int qrow = qt * 64 + wv * 16 + l15;

  const short* qp = qbuf + (size_t)(b * T + qrow) * D;
  bf16x8 qf0 = *(const bf16x8*)(qp + quad * 8);
  bf16x8 qf1 = *(const bf16x8*)(qp + 32 + quad * 8);

  const int srow = tid >> 2, soff = (tid & 3) * 16;
  const short* kbb = kbuf + (size_t)b * T * D;
  const short* vbb = vT + (size_t)b * D * T;

  f32x4 o[4] = {};
  float lsum = 0.f;

  for (int base = kt0; base < kt1; base += 3) {
    const int nt3 = min(3, kt1 - base);
    if (base > kt0) __syncthreads();
    for (int t3 = 0; t3 < nt3; ++t3) {
      const bf16x8* kp = (const bf16x8*)(kbb + (size_t)((base + t3) * 64 + srow) * D + soff);
      bf16x8 k0 = kp[0], k1 = kp[1];
      const bf16x8* vp = (const bf16x8*)(vbb + (size_t)srow * T + (base + t3) * 64 + soff);
      bf16x8 v0 = vp[0], v1 = vp[1];
      *(bf16x8*)&Ks[t3 * 64 + srow][soff] = k0;
      *(bf16x8*)&Ks[t3 * 64 + srow][soff + 8] = k1;
      *(bf16x8*)&Vs[srow][t3 * 64 + soff] = v0;
      *(bf16x8*)&Vs[srow][t3 * 64 + soff + 8] = v1;
    }
    __syncthreads();

    for (int tt = 0; tt < nt3; ++tt) {
      const int kt = base + tt;
      f32x4 s[4] = {};
#pragma unroll
      for (int nt = 0; nt < 4; ++nt) {
        bf16x8 ka0 = *(const bf16x8*)&Ks[tt * 64 + nt * 16 + l15][quad * 8];
        bf16x8 ka1 = *(const bf16x8*)&Ks[tt * 64 + nt * 16 + l15][32 + quad * 8];
        s[nt] = MFMA(ka1, qf1, MFMA(ka0, qf0, s[nt]));
      }
      const bool diag = (kt == qt);
#pragma unroll
      for (int nt = 0; nt < 4; ++nt) {
#pragma unroll
        for (int r = 0; r < 4; ++r) {
          float p = exp2f(s[nt][r]);
          if (diag) {
            int key = kt * 64 + nt * 16 + quad * 4 + r;
            if (key > qrow) p = 0.f;
          }
          lsum += p;
          s[nt][r] = p;
        }
      }
#if HAVE_MFMA16
#pragma unroll
      for (int nt = 0; nt < 4; ++nt) {
        bf16x4 pb;
        pb[0] = f2bf(s[nt][0]); pb[1] = f2bf(s[nt][1]);
        pb[2] = f2bf(s[nt][2]); pb[3] = f2bf(s[nt][3]);
#pragma unroll
        for (int dt = 0; dt < 4; ++dt) {
          bf16x4 va = *(const bf16x4*)&Vs[dt * 16 + l15][tt * 64 + nt * 16 + quad * 4];
          o[dt] = MFMA16(va, pb, o[dt]);
        }
      }
#else
#pragma unroll
      for (int h = 0; h < 2; ++h) {
        union { short2 s2; int i2; } a01, a23, b01, b23;
        a01.s2 = make_short2(f2bf(s[2 * h][0]), f2bf(s[2 * h][1]));
        a23.s2 = make_short2(f2bf(s[2 * h][2]), f2bf(s[2 * h][3]));
        b01.s2 = make_short2(f2bf(s[2 * h + 1][0]), f2bf(s[2 * h + 1][1]));
        b23.s2 = make_short2(f2bf(s[2 * h + 1][2]), f2bf(s[2 * h + 1][3]));
        const int srcA = l15 + ((quad & 1) << 5);
        const int srcB = srcA + 16;
        int gA01 = __shfl(a01.i2, srcA), gA01b = __shfl(b01.i2, srcA);
        int gA23 = __shfl(a23.i2, srcA), gA23b = __shfl(b23.i2, srcA);
        int gB01 = __shfl(a01.i2, srcB), gB01b = __shfl(b01.i2, srcB);
        int gB23 = __shfl(a23.i2, srcB), gB23b = __shfl(b23.i2, srcB);
        union { int d[4]; bf16x8 v; } pf;
        const bool lo = (quad < 2);
        pf.d[0] = lo ? gA01 : gA01b;
        pf.d[1] = lo ? gA23 : gA23b;
        pf.d[2] = lo ? gB01 : gB01b;
        pf.d[3] = lo ? gB23 : gB23b;
#pragma unroll
        for (int dt = 0; dt < 4; ++dt) {
          bf16x8 va = *(const bf16x8*)&Vs[dt * 16 + l15][tt * 64 + h * 32 + quad * 8];
          o[dt] = MFMA(va, pf.v, o[dt]);
        }
      }
#endif
    }
  }

  float lv = lsum;
  lv += __shfl_xor(lv, 16);
  lv += __shfl_xor(lv, 32);

  if (kt0 == 0 && kt1 == qt + 1) {
    const float inv = 1.0f / lv;
    float* op = out + (size_t)(b * T + qrow) * D;
#pragma unroll
    for (int dt = 0; dt < 4; ++dt)
      *(float4*)(op + dt * 16 + quad * 4) =
          make_float4(o[dt][0] * inv, o[dt][1] * inv, o[dt][2] * inv, o[dt][3] * inv);
  } else {
    const int prow = b * T + qrow;
    float* pp = Opart + ((size_t)c * 16384 + prow) * D;
#pragma unroll
    for (int dt = 0; dt < 4; ++dt)
      *(float4*)(pp + dt * 16 + quad * 4) =
          make_float4(o[dt][0], o[dt][1], o[dt][2], o[dt][3]);
    if (quad == 0) lpart[c * 16384 + prow] = lv;
  }
}

// ---------------------------------------------------------------------------
// Kernel 4: combine split-K partials for rows with >=2 chunks (qrow >= 192).
// ---------------------------------------------------------------------------
__global__ __launch_bounds__(256) void combine_k(
    const float* __restrict__ Opart, const float* __restrict__ lpart,
    float* __restrict__ out) {
  const int gid = blockIdx.x * 256 + threadIdx.x;  // 928*256 = 237568
  const int r16 = gid >> 4;                        // 0..14847
  const int b = r16 / 1856;
  const int qrow = 192 + (r16 - b * 1856);
  const int row = b * T + qrow;
  const int d4 = (gid & 15) << 2;
  const int nc = (qrow >> 6) / 3 + 1;  // 2..11 chunks
  float a0 = 0.f, a1 = 0.f, a2 = 0.f, a3 = 0.f, l = 0.f;
  for (int c = 0; c < nc; ++c) {
    const float4 t = *(const float4*)(Opart + ((size_t)c * 16384 + row) * D + d4);
    a0 += t.x; a1 += t.y; a2 += t.z; a3 += t.w;
    l += lpart[c * 16384 + row];
  }
  const float inv = 1.0f / l;
  *(float4*)(out + (size_t)row * D + d4) = make_float4(a0 * inv, a1 * inv, a2 * inv, a3 * inv);
}

// ---------------------------------------------------------------------------
extern "C" void kernel_launch(void* const* d_in, const int* in_sizes, int n_in,
                              void* d_out, int out_size, void* d_ws, size_t ws_size,
                              hipStream_t stream) {
  const float* x  = (const float*)d_in[0];
  const float* Wk = (const float*)d_in[1];
  const float* Wq = (const float*)d_in[2];
  const float* Wv = (const float*)d_in[3];
  float* out = (float*)d_out;

  const size_t M = (size_t)BATCH * T * D;  // 1,048,576 elements
  short* qb = (short*)d_ws;
  short* kb = qb + M;
  short* vT = kb + M;
  short* Wt = vT + M;                       // 196,608 shorts
  float* Opart = (float*)(Wt + 196608);
  float* lpart = Opart + (size_t)NCHUNK_MAX * 16384 * 64;

  const size_t need = (3 * M + 196608) * 2 +
                      ((size_t)NCHUNK_MAX * 16384 * 64 + (size_t)NCHUNK_MAX * 16384) * 4;
  const bool split = ws_size >= need;

  prep_w<<<dim3(16, 3), 256, 0, stream>>>(Wq, Wk, Wv, Wt);
  proj_mfma<<<dim3(512), 256, 0, stream>>>(x, Wt, qb, kb, vT);
  if (split) {
    attn_mfma<<<dim3(1496), 256, 0, stream>>>(qb, kb, vT, out, Opart, lpart, 1);
    combine_k<<<dim3(928), 256, 0, stream>>>(Opart, lpart, out);
  } else {
    attn_mfma<<<dim3(256), 256, 0, stream>>>(qb, kb, vT, out, Opart, lpart, 0);
  }
}